// Round 14
// baseline (367.896 us; speedup 1.0000x reference)
//
#include <hip/hip_runtime.h>

#define M_ROWS 200000
#define NROWS  64            // rows per block = lanes per wave
#define NBLK   3125          // 200000 / 64, exact
#define DIM1   320
#define OUTD   416
#define FSTR   196           // featV row stride (floats); 196 mod 32 = 4 -> conflict-free (R12/13: 0)
#define LDS_FLOATS (NROWS * FSTR)   // 12544 floats = 50176 B

typedef __attribute__((ext_vector_type(4))) float f32x4;

static __device__ __forceinline__ float4 ld4(const float* p) {
    return *reinterpret_cast<const float4*>(p);
}

// R13 + fused F2/F3/F4: one pass over the LDS v-streams feeds w110 (out0-D),
// w101 (out1-e) and w112 (out2-G) simultaneously -> ds_read_b128 per thread
// 144 -> 48, three serial stall chains -> one. Weight addresses stay wave-
// uniform (SGPR s_load stream). launch_bounds(512,3): VGPR target 170 gives
// the ~120-reg live set slack (the (512,4)=128 cap risks R8-style spill;
// tripwire = WRITE_SIZE inflation).
__global__ __launch_bounds__(512, 3)
void tp_valu_v14(const float* __restrict__ x1,
                 const float* __restrict__ x2,
                 const float* __restrict__ w000,
                 const float* __restrict__ w011,
                 const float* __restrict__ w101,
                 const float* __restrict__ w110,
                 const float* __restrict__ w112,
                 float* __restrict__ out) {
    __shared__ __align__(16) float featV[LDS_FLOATS];

    constexpr float INV3 = 0.57735026918962576f;   // 1/sqrt(3)
    constexpr float INV6 = 0.40824829046386302f;   // 1/sqrt(6)

    const int t   = threadIdx.x;
    const int row = t & 63;
    const int q   = t >> 6;                        // wave id 0..7
    const int wv  = __builtin_amdgcn_readfirstlane(q);
    const long rbase = (long)blockIdx.x * NROWS;

    const float* x1r = x1 + (rbase + row) * DIM1;
    float* frS = featV + row * FSTR;

    // per-row x2-derived constants, kept in registers for the whole kernel
    const float4 xr2 = ld4(x2 + (rbase + row) * 4);
    const float s2  = xr2.x;
    const float s2I = s2 * INV3;
    const float vxI = xr2.y * INV3, vyI = xr2.z * INV3, vzI = xr2.w * INV3;
    const float v6x = xr2.y * INV6, v6y = xr2.z * INV6, v6z = xr2.w * INV6;

    // ---- stage featV = [v0 (0:64) | v1 (64:128) | v2 (128:192)]; wave q covers u=8q..8q+7 ----
    {
        float qf[24];
        #pragma unroll
        for (int c = 0; c < 6; ++c) {
            float4 v = ld4(x1r + 128 + 24*q + 4*c);
            qf[4*c+0]=v.x; qf[4*c+1]=v.y; qf[4*c+2]=v.z; qf[4*c+3]=v.w;
        }
        #pragma unroll
        for (int i = 0; i < 8; ++i) {
            const int u = 8*q + i;
            frS[u]       = qf[3*i+0];
            frS[64 + u]  = qf[3*i+1];
            frS[128 + u] = qf[3*i+2];
        }
    }
    __syncthreads();                               // the kernel's ONLY barrier

    const int c16 = wv * 16, c8w = wv * 8, c4w = wv * 4;

    // ---- F1: ONE x1s pass (global, per-lane row) -> accA[16] (w000) + accB[8] (w011) ----
    float accA[16], accB[8];
    #pragma unroll
    for (int i = 0; i < 16; ++i) accA[i] = 0.f;
    #pragma unroll
    for (int i = 0; i < 8; ++i) accB[i] = 0.f;
    {
        const float* wa = w000 + c16;
        const float* wb = w011 + c8w;
        #pragma unroll 2
        for (int kt = 0; kt < 16; ++kt) {          // 8 k per tile
            f32x4 xs0 = *reinterpret_cast<const f32x4*>(x1r + kt*8);
            f32x4 xs1 = *reinterpret_cast<const f32x4*>(x1r + kt*8 + 4);
            #pragma unroll
            for (int j = 0; j < 8; ++j) {
                const float fv = (j < 4) ? xs0[j] : xs1[j-4];
                const float* wpA = wa + (size_t)(kt*8 + j) * 128;
                const float* wpB = wb + (size_t)(kt*8 + j) * 64;
                #pragma unroll
                for (int c = 0; c < 4; ++c) {
                    float4 w = ld4(wpA + 4*c);
                    accA[4*c+0] += fv*w.x; accA[4*c+1] += fv*w.y;
                    accA[4*c+2] += fv*w.z; accA[4*c+3] += fv*w.w;
                }
                #pragma unroll
                for (int c = 0; c < 2; ++c) {
                    float4 w = ld4(wpB + 4*c);
                    accB[4*c+0] += fv*w.x; accB[4*c+1] += fv*w.y;
                    accB[4*c+2] += fv*w.z; accB[4*c+3] += fv*w.w;
                }
            }
        }
    }
    #pragma unroll
    for (int i = 0; i < 16; ++i) accA[i] *= s2;    // out0 = s2*A + (d @ w110)

    // ---- fused F2+F3+F4: ONE pass over LDS v-streams feeds w110/w101/w112 ----
    float e0[8], e1[8], e2[8];
    float g0[4], g1[4], g2[4];
    #pragma unroll
    for (int i = 0; i < 8; ++i) { e0[i]=0.f; e1[i]=0.f; e2[i]=0.f; }
    #pragma unroll
    for (int i = 0; i < 4; ++i) { g0[i]=0.f; g1[i]=0.f; g2[i]=0.f; }
    {
        const float* wD = w110 + c16;
        const float* wE = w101 + c8w;
        const float* wG = w112 + c4w;
        #pragma unroll 1
        for (int ut = 0; ut < 8; ++ut) {           // 8 u per tile
            f32x4 a0 = *reinterpret_cast<const f32x4*>(frS + 8*ut);
            f32x4 a1 = *reinterpret_cast<const f32x4*>(frS + 8*ut + 4);
            f32x4 b0 = *reinterpret_cast<const f32x4*>(frS + 64 + 8*ut);
            f32x4 b1 = *reinterpret_cast<const f32x4*>(frS + 64 + 8*ut + 4);
            f32x4 c0 = *reinterpret_cast<const f32x4*>(frS + 128 + 8*ut);
            f32x4 c1 = *reinterpret_cast<const f32x4*>(frS + 128 + 8*ut + 4);
            #pragma unroll
            for (int j = 0; j < 8; ++j) {
                const float fa = (j < 4) ? a0[j] : a1[j-4];
                const float fb = (j < 4) ? b0[j] : b1[j-4];
                const float fc = (j < 4) ? c0[j] : c1[j-4];
                const float fd = fa*vxI + fb*vyI + fc*vzI;   // d*INV3
                const int  u  = 8*ut + j;

                // w110 -> accA (16 cols)
                const float* wp = wD + (size_t)u * 128;
                #pragma unroll
                for (int c = 0; c < 4; ++c) {
                    float4 w = ld4(wp + 4*c);
                    accA[4*c+0] += fd*w.x; accA[4*c+1] += fd*w.y;
                    accA[4*c+2] += fd*w.z; accA[4*c+3] += fd*w.w;
                }
                // w101 -> e[3] (8 cols)
                const float* wq = wE + (size_t)u * 64;
                #pragma unroll
                for (int c = 0; c < 2; ++c) {
                    float4 w = ld4(wq + 4*c);
                    e0[4*c+0] += fa*w.x; e0[4*c+1] += fa*w.y;
                    e0[4*c+2] += fa*w.z; e0[4*c+3] += fa*w.w;
                    e1[4*c+0] += fb*w.x; e1[4*c+1] += fb*w.y;
                    e1[4*c+2] += fb*w.z; e1[4*c+3] += fb*w.w;
                    e2[4*c+0] += fc*w.x; e2[4*c+1] += fc*w.y;
                    e2[4*c+2] += fc*w.z; e2[4*c+3] += fc*w.w;
                }
                // w112 -> g[3] (4 cols)
                float4 w = ld4(wG + (size_t)u * 32);
                g0[0] += fa*w.x; g0[1] += fa*w.y; g0[2] += fa*w.z; g0[3] += fa*w.w;
                g1[0] += fb*w.x; g1[1] += fb*w.y; g1[2] += fb*w.z; g1[3] += fb*w.w;
                g2[0] += fc*w.x; g2[1] += fc*w.y; g2[2] += fc*w.z; g2[3] += fc*w.w;
            }
        }
    }

    // ---- store out0: 64 B contiguous per lane (8 waves cover cols 0..127) ----
    {
        float* orow = out + (rbase + row)*OUTD + c16;
        #pragma unroll
        for (int i = 0; i < 4; ++i)
            *reinterpret_cast<float4*>(orow + 4*i) =
                make_float4(accA[4*i], accA[4*i+1], accA[4*i+2], accA[4*i+3]);
    }

    // ---- out1 epilogue + store: 96 B contiguous per lane at 128 + wv*24 ----
    {
        float vals[24];
        #pragma unroll
        for (int c = 0; c < 8; ++c) {
            const float b = accB[c];
            vals[3*c+0] = vxI*b + s2I*e0[c];
            vals[3*c+1] = vyI*b + s2I*e1[c];
            vals[3*c+2] = vzI*b + s2I*e2[c];
        }
        float* orow = out + (rbase + row)*OUTD + 128 + wv*24;
        #pragma unroll
        for (int i = 0; i < 6; ++i)
            *reinterpret_cast<float4*>(orow + 4*i) =
                make_float4(vals[4*i], vals[4*i+1], vals[4*i+2], vals[4*i+3]);
    }

    // ---- out2 epilogue: cross(G, v)*INV6, 48 B contiguous per lane at 320 + wv*12 ----
    {
        float ov[12];
        #pragma unroll
        for (int wl = 0; wl < 4; ++wl) {
            ov[3*wl+0] = g1[wl]*v6z - g2[wl]*v6y;
            ov[3*wl+1] = g2[wl]*v6x - g0[wl]*v6z;
            ov[3*wl+2] = g0[wl]*v6y - g1[wl]*v6x;
        }
        float* orow = out + (rbase + row)*OUTD + 320 + wv*12;
        #pragma unroll
        for (int i = 0; i < 3; ++i)
            *reinterpret_cast<float4*>(orow + 4*i) =
                make_float4(ov[4*i], ov[4*i+1], ov[4*i+2], ov[4*i+3]);
    }
}

extern "C" void kernel_launch(void* const* d_in, const int* in_sizes, int n_in,
                              void* d_out, int out_size, void* d_ws, size_t ws_size,
                              hipStream_t stream) {
    const float* x1   = (const float*)d_in[0];
    const float* x2   = (const float*)d_in[1];
    const float* w000 = (const float*)d_in[2];
    const float* w011 = (const float*)d_in[3];
    const float* w101 = (const float*)d_in[4];
    const float* w110 = (const float*)d_in[5];
    const float* w112 = (const float*)d_in[6];
    // d_in[7] = w3j111 — folded analytically (cross with v2, scaled 1/sqrt6).
    float* out = (float*)d_out;

    tp_valu_v14<<<dim3(NBLK), dim3(512), 0, stream>>>(
        x1, x2, w000, w011, w101, w110, w112, out);
}

// Round 15
// 331.820 us; speedup vs baseline: 1.1087x; 1.1087x over previous
//
#include <hip/hip_runtime.h>

#define M_ROWS 200000
#define NROWS  64            // rows per block = lanes per wave
#define NBLK   3125          // 200000 / 64, exact
#define DIM1   320
#define OUTD   416
#define FSTR   196           // featV row stride (floats); measured 0 conflicts (R12/R13)
#define XG     66            // xs granule stride (16B units) per kt: consumption conflict-free
#define LDS_FLOATS (NROWS * FSTR)   // 12544 floats = 50176 B (featV); xs overlay = 33792 B

typedef __attribute__((ext_vector_type(4))) float f32x4;

static __device__ __forceinline__ float4 ld4(const float* p) {
    return *reinterpret_cast<const float4*>(p);
}

// R13 pass structure (best: 326us) + coalesced x1 ingestion. R13/R14 read x1
// per-lane-row (64 cache lines per VMEM inst, ~64 TA cycles each; ~99us chip-wide
// serialization). Now: x1s staged coalesced into a transposed LDS tile
// xs[kt][row] (b128 consumption = 64 lanes reading 1024 contiguous B), v-stream
// staging reads coalesced + scalar scatter writes. xs region is overlaid by
// featV after F1 (barrier) -> LDS unchanged. R14's fusion reverted (it cost 41us).
__global__ __launch_bounds__(512, 3)
void tp_valu_v15(const float* __restrict__ x1,
                 const float* __restrict__ x2,
                 const float* __restrict__ w000,
                 const float* __restrict__ w011,
                 const float* __restrict__ w101,
                 const float* __restrict__ w110,
                 const float* __restrict__ w112,
                 float* __restrict__ out) {
    __shared__ __align__(16) float lds[LDS_FLOATS];
    float* featV = lds;
    char*  ldsb  = reinterpret_cast<char*>(lds);

    constexpr float INV3 = 0.57735026918962576f;   // 1/sqrt(3)
    constexpr float INV6 = 0.40824829046386302f;   // 1/sqrt(6)

    const int t   = threadIdx.x;
    const int row = t & 63;
    const int q   = t >> 6;                        // wave id 0..7
    const int wv  = __builtin_amdgcn_readfirstlane(q);
    const long rbase = (long)blockIdx.x * NROWS;

    // per-row x2-derived constants, registers for the whole kernel
    const float4 xr2 = ld4(x2 + (rbase + row) * 4);
    const float s2  = xr2.x;
    const float s2I = s2 * INV3;
    const float vxI = xr2.y * INV3, vyI = xr2.z * INV3, vzI = xr2.w * INV3;
    const float v6x = xr2.y * INV6, v6y = xr2.z * INV6, v6z = xr2.w * INV6;

    // ---- stage xs: x1s -> transposed LDS tile, COALESCED global reads ----
    // thread covers 4 float4s: g = i*512+t, r = g>>5, j = g&31 (k-chunk)
    #pragma unroll
    for (int i = 0; i < 4; ++i) {
        const int g = i * 512 + t;
        const int r = g >> 5, j = g & 31;
        float4 v = ld4(x1 + (rbase + r) * DIM1 + j * 4);
        *reinterpret_cast<float4*>(ldsb + (size_t)(j * XG + r) * 16) = v;
    }
    __syncthreads();

    const int c16 = wv * 16, c8w = wv * 8, c4w = wv * 4;

    // ---- F1: x1s pass from LDS (conflict-free b128) -> accA[16] (w000) + accB[8] (w011) ----
    float accA[16], accB[8];
    #pragma unroll
    for (int i = 0; i < 16; ++i) accA[i] = 0.f;
    #pragma unroll
    for (int i = 0; i < 8; ++i) accB[i] = 0.f;
    {
        const float* wa = w000 + c16;
        const float* wb = w011 + c8w;
        #pragma unroll 2
        for (int kt = 0; kt < 32; ++kt) {          // 4 k per tile
            f32x4 xs4 = *reinterpret_cast<const f32x4*>(ldsb + (size_t)(kt * XG + row) * 16);
            #pragma unroll
            for (int e = 0; e < 4; ++e) {
                const float fv = xs4[e];
                const int k = kt * 4 + e;
                const float* wpA = wa + (size_t)k * 128;
                const float* wpB = wb + (size_t)k * 64;
                #pragma unroll
                for (int c = 0; c < 4; ++c) {
                    float4 w = ld4(wpA + 4*c);
                    accA[4*c+0] += fv*w.x; accA[4*c+1] += fv*w.y;
                    accA[4*c+2] += fv*w.z; accA[4*c+3] += fv*w.w;
                }
                #pragma unroll
                for (int c = 0; c < 2; ++c) {
                    float4 w = ld4(wpB + 4*c);
                    accB[4*c+0] += fv*w.x; accB[4*c+1] += fv*w.y;
                    accB[4*c+2] += fv*w.z; accB[4*c+3] += fv*w.w;
                }
            }
        }
    }
    #pragma unroll
    for (int i = 0; i < 16; ++i) accA[i] *= s2;    // out0 = s2*A + (d @ w110)
    __syncthreads();                               // xs dead; featV may overwrite

    // ---- stage featV = [v0|v1|v2] per row (FSTR 196), COALESCED global reads ----
    // thread covers 6 float4s of the block's x1v: g = i*512+t, r = g/48, j = g%48
    #pragma unroll
    for (int i = 0; i < 6; ++i) {
        const int g = i * 512 + t;
        const int r = g / 48, j = g % 48;
        f32x4 v = *reinterpret_cast<const f32x4*>(x1 + (rbase + r) * DIM1 + 128 + j * 4);
        #pragma unroll
        for (int e = 0; e < 4; ++e) {
            const int p  = j * 4 + e;              // 0..191
            const int u  = p / 3;
            const int cm = p - 3 * u;
            featV[r * FSTR + cm * 64 + u] = v[e];
        }
    }
    __syncthreads();

    const float* frS = featV + row * FSTR;

    // ---- F2: d pass (LDS v streams) -> accA += (x1v.v2)*INV3 @ w110 ----
    {
        const float* wa = w110 + c16;
        #pragma unroll 2
        for (int ut = 0; ut < 8; ++ut) {           // 8 u per tile
            f32x4 a0 = *reinterpret_cast<const f32x4*>(frS + 8*ut);
            f32x4 a1 = *reinterpret_cast<const f32x4*>(frS + 8*ut + 4);
            f32x4 b0 = *reinterpret_cast<const f32x4*>(frS + 64 + 8*ut);
            f32x4 b1 = *reinterpret_cast<const f32x4*>(frS + 64 + 8*ut + 4);
            f32x4 c0 = *reinterpret_cast<const f32x4*>(frS + 128 + 8*ut);
            f32x4 c1 = *reinterpret_cast<const f32x4*>(frS + 128 + 8*ut + 4);
            float d[8];
            #pragma unroll
            for (int j = 0; j < 4; ++j) {
                d[j]   = a0[j]*vxI + b0[j]*vyI + c0[j]*vzI;
                d[4+j] = a1[j]*vxI + b1[j]*vyI + c1[j]*vzI;
            }
            #pragma unroll
            for (int j = 0; j < 8; ++j) {
                const float fv = d[j];
                const float* wp = wa + (size_t)(8*ut + j) * 128;
                #pragma unroll
                for (int c = 0; c < 4; ++c) {
                    float4 w = ld4(wp + 4*c);
                    accA[4*c+0] += fv*w.x; accA[4*c+1] += fv*w.y;
                    accA[4*c+2] += fv*w.z; accA[4*c+3] += fv*w.w;
                }
            }
        }
    }
    // store out0: 64 B contiguous per lane (8 waves cover cols 0..127)
    {
        float* orow = out + (rbase + row)*OUTD + c16;
        #pragma unroll
        for (int i = 0; i < 4; ++i)
            *reinterpret_cast<float4*>(orow + 4*i) =
                make_float4(accA[4*i], accA[4*i+1], accA[4*i+2], accA[4*i+3]);
    }

    // ---- F3: e pass (LDS v streams) -> e[3][8] (w101); combine with held accB ----
    float e0[8], e1[8], e2[8];
    #pragma unroll
    for (int i = 0; i < 8; ++i) { e0[i]=0.f; e1[i]=0.f; e2[i]=0.f; }
    {
        const float* wb = w101 + c8w;
        #pragma unroll 2
        for (int ut = 0; ut < 8; ++ut) {
            f32x4 a0 = *reinterpret_cast<const f32x4*>(frS + 8*ut);
            f32x4 a1 = *reinterpret_cast<const f32x4*>(frS + 8*ut + 4);
            f32x4 b0 = *reinterpret_cast<const f32x4*>(frS + 64 + 8*ut);
            f32x4 b1 = *reinterpret_cast<const f32x4*>(frS + 64 + 8*ut + 4);
            f32x4 c0 = *reinterpret_cast<const f32x4*>(frS + 128 + 8*ut);
            f32x4 c1 = *reinterpret_cast<const f32x4*>(frS + 128 + 8*ut + 4);
            #pragma unroll
            for (int j = 0; j < 8; ++j) {
                const float fa = (j < 4) ? a0[j] : a1[j-4];
                const float fb = (j < 4) ? b0[j] : b1[j-4];
                const float fc = (j < 4) ? c0[j] : c1[j-4];
                const float* wp = wb + (size_t)(8*ut + j) * 64;
                #pragma unroll
                for (int c = 0; c < 2; ++c) {
                    float4 w = ld4(wp + 4*c);
                    e0[4*c+0] += fa*w.x; e0[4*c+1] += fa*w.y;
                    e0[4*c+2] += fa*w.z; e0[4*c+3] += fa*w.w;
                    e1[4*c+0] += fb*w.x; e1[4*c+1] += fb*w.y;
                    e1[4*c+2] += fb*w.z; e1[4*c+3] += fb*w.w;
                    e2[4*c+0] += fc*w.x; e2[4*c+1] += fc*w.y;
                    e2[4*c+2] += fc*w.z; e2[4*c+3] += fc*w.w;
                }
            }
        }
    }
    // out1 epilogue + store: 96 B contiguous per lane at 128 + wv*24
    {
        float vals[24];
        #pragma unroll
        for (int c = 0; c < 8; ++c) {
            const float b = accB[c];
            vals[3*c+0] = vxI*b + s2I*e0[c];
            vals[3*c+1] = vyI*b + s2I*e1[c];
            vals[3*c+2] = vzI*b + s2I*e2[c];
        }
        float* orow = out + (rbase + row)*OUTD + 128 + wv*24;
        #pragma unroll
        for (int i = 0; i < 6; ++i)
            *reinterpret_cast<float4*>(orow + 4*i) =
                make_float4(vals[4*i], vals[4*i+1], vals[4*i+2], vals[4*i+3]);
    }

    // ---- F4: G pass (LDS v streams) -> g[3][4] (w112); cross epilogue ----
    float g0[4], g1[4], g2[4];
    #pragma unroll
    for (int i = 0; i < 4; ++i) { g0[i]=0.f; g1[i]=0.f; g2[i]=0.f; }
    {
        const float* wb = w112 + c4w;
        #pragma unroll 2
        for (int ut = 0; ut < 8; ++ut) {
            f32x4 a0 = *reinterpret_cast<const f32x4*>(frS + 8*ut);
            f32x4 a1 = *reinterpret_cast<const f32x4*>(frS + 8*ut + 4);
            f32x4 b0 = *reinterpret_cast<const f32x4*>(frS + 64 + 8*ut);
            f32x4 b1 = *reinterpret_cast<const f32x4*>(frS + 64 + 8*ut + 4);
            f32x4 c0 = *reinterpret_cast<const f32x4*>(frS + 128 + 8*ut);
            f32x4 c1 = *reinterpret_cast<const f32x4*>(frS + 128 + 8*ut + 4);
            #pragma unroll
            for (int j = 0; j < 8; ++j) {
                const float fa = (j < 4) ? a0[j] : a1[j-4];
                const float fb = (j < 4) ? b0[j] : b1[j-4];
                const float fc = (j < 4) ? c0[j] : c1[j-4];
                float4 w = ld4(wb + (size_t)(8*ut + j) * 32);
                const float wvv[4] = {w.x, w.y, w.z, w.w};
                #pragma unroll
                for (int wl = 0; wl < 4; ++wl) {
                    g0[wl] += fa * wvv[wl];
                    g1[wl] += fb * wvv[wl];
                    g2[wl] += fc * wvv[wl];
                }
            }
        }
    }
    // out2 epilogue: cross(G, v)*INV6, 48 B contiguous per lane at 320 + wv*12
    {
        float ov[12];
        #pragma unroll
        for (int wl = 0; wl < 4; ++wl) {
            ov[3*wl+0] = g1[wl]*v6z - g2[wl]*v6y;
            ov[3*wl+1] = g2[wl]*v6x - g0[wl]*v6z;
            ov[3*wl+2] = g0[wl]*v6y - g1[wl]*v6x;
        }
        float* orow = out + (rbase + row)*OUTD + 320 + wv*12;
        #pragma unroll
        for (int i = 0; i < 3; ++i)
            *reinterpret_cast<float4*>(orow + 4*i) =
                make_float4(ov[4*i], ov[4*i+1], ov[4*i+2], ov[4*i+3]);
    }
}

extern "C" void kernel_launch(void* const* d_in, const int* in_sizes, int n_in,
                              void* d_out, int out_size, void* d_ws, size_t ws_size,
                              hipStream_t stream) {
    const float* x1   = (const float*)d_in[0];
    const float* x2   = (const float*)d_in[1];
    const float* w000 = (const float*)d_in[2];
    const float* w011 = (const float*)d_in[3];
    const float* w101 = (const float*)d_in[4];
    const float* w110 = (const float*)d_in[5];
    const float* w112 = (const float*)d_in[6];
    // d_in[7] = w3j111 — folded analytically (cross with v2, scaled 1/sqrt6).
    float* out = (float*)d_out;

    tp_valu_v15<<<dim3(NBLK), dim3(512), 0, stream>>>(
        x1, x2, w000, w011, w101, w110, w112, out);
}

// Round 16
// 316.978 us; speedup vs baseline: 1.1606x; 1.0468x over previous
//
#include <hip/hip_runtime.h>

#define M_ROWS 200000
#define NROWS  64            // rows per block = lanes per wave
#define NBLK   3125          // 200000 / 64, exact
#define DIM1   320
#define OUTD   416
#define FSTR   196           // featV row stride (floats); measured 0 conflicts (R12/R13)
#define LDS_FLOATS (NROWS * FSTR)   // 12544 floats = 50176 B

typedef __attribute__((ext_vector_type(4))) float f32x4;
typedef __attribute__((ext_vector_type(2))) float f32x2;

static __device__ __forceinline__ float4 ld4(const float* p) {
    return *reinterpret_cast<const float4*>(p);
}
static __device__ __forceinline__ f32x2 ld2(const float* p) {
    return *reinterpret_cast<const f32x2*>(p);
}

// R13 (best: 326us) with every accumulator block rewritten as f32x2 vector
// math: HIP's -ffp-contract=fast + LLVM's FeaturePackedFP32Ops should select
// v_pk_fma_f32 (2 fp32 FMA/lane/inst) -> FMA issue floor 136us -> ~68us.
// Weight f32x2 loads stay wave-uniform (SGPR pairs; one 64-bit SGPR operand
// per VOP3P inst is legal). Staging, passes, stores identical to R13.
__global__ __launch_bounds__(512, 4)
void tp_valu_v16(const float* __restrict__ x1,
                 const float* __restrict__ x2,
                 const float* __restrict__ w000,
                 const float* __restrict__ w011,
                 const float* __restrict__ w101,
                 const float* __restrict__ w110,
                 const float* __restrict__ w112,
                 float* __restrict__ out) {
    __shared__ __align__(16) float featV[LDS_FLOATS];

    constexpr float INV3 = 0.57735026918962576f;   // 1/sqrt(3)
    constexpr float INV6 = 0.40824829046386302f;   // 1/sqrt(6)

    const int t   = threadIdx.x;
    const int row = t & 63;
    const int q   = t >> 6;                        // wave id 0..7
    const int wv  = __builtin_amdgcn_readfirstlane(q);
    const long rbase = (long)blockIdx.x * NROWS;

    const float* x1r = x1 + (rbase + row) * DIM1;
    float* frS = featV + row * FSTR;

    // per-row x2-derived constants, registers for the whole kernel
    const float4 xr2 = ld4(x2 + (rbase + row) * 4);
    const float s2  = xr2.x;
    const float s2I = s2 * INV3;
    const float vxI = xr2.y * INV3, vyI = xr2.z * INV3, vzI = xr2.w * INV3;
    const float v6x = xr2.y * INV6, v6y = xr2.z * INV6, v6z = xr2.w * INV6;

    // ---- stage featV = [v0 (0:64) | v1 (64:128) | v2 (128:192)]; wave q covers u=8q..8q+7 ----
    {
        float qf[24];
        #pragma unroll
        for (int c = 0; c < 6; ++c) {
            float4 v = ld4(x1r + 128 + 24*q + 4*c);
            qf[4*c+0]=v.x; qf[4*c+1]=v.y; qf[4*c+2]=v.z; qf[4*c+3]=v.w;
        }
        #pragma unroll
        for (int i = 0; i < 8; ++i) {
            const int u = 8*q + i;
            frS[u]       = qf[3*i+0];
            frS[64 + u]  = qf[3*i+1];
            frS[128 + u] = qf[3*i+2];
        }
    }
    __syncthreads();                               // the kernel's ONLY barrier

    const int c16 = wv * 16, c8w = wv * 8, c4w = wv * 4;

    // ---- F1: ONE x1s pass (global, per-lane row) -> accA (w000, 16 cols) + accB (w011, 8 cols) ----
    f32x2 accA[8], accB[4];
    #pragma unroll
    for (int i = 0; i < 8; ++i) accA[i] = (f32x2){0.f, 0.f};
    #pragma unroll
    for (int i = 0; i < 4; ++i) accB[i] = (f32x2){0.f, 0.f};
    {
        const float* wa = w000 + c16;
        const float* wb = w011 + c8w;
        #pragma unroll 2
        for (int kt = 0; kt < 16; ++kt) {          // 8 k per tile
            f32x4 xs0 = *reinterpret_cast<const f32x4*>(x1r + kt*8);
            f32x4 xs1 = *reinterpret_cast<const f32x4*>(x1r + kt*8 + 4);
            #pragma unroll
            for (int j = 0; j < 8; ++j) {
                const float fv = (j < 4) ? xs0[j] : xs1[j-4];
                const f32x2 fvv = {fv, fv};
                const float* wpA = wa + (size_t)(kt*8 + j) * 128;
                const float* wpB = wb + (size_t)(kt*8 + j) * 64;
                #pragma unroll
                for (int c = 0; c < 8; ++c)
                    accA[c] += ld2(wpA + 2*c) * fvv;
                #pragma unroll
                for (int c = 0; c < 4; ++c)
                    accB[c] += ld2(wpB + 2*c) * fvv;
            }
        }
    }
    {
        const f32x2 s2v = {s2, s2};
        #pragma unroll
        for (int i = 0; i < 8; ++i) accA[i] *= s2v;   // out0 = s2*A + (d @ w110)
    }

    // ---- F2: d pass (LDS v streams) -> accA += (x1v.v2)*INV3 @ w110 ----
    {
        const float* wa = w110 + c16;
        #pragma unroll 2
        for (int ut = 0; ut < 8; ++ut) {           // 8 u per tile
            f32x4 a0 = *reinterpret_cast<const f32x4*>(frS + 8*ut);
            f32x4 a1 = *reinterpret_cast<const f32x4*>(frS + 8*ut + 4);
            f32x4 b0 = *reinterpret_cast<const f32x4*>(frS + 64 + 8*ut);
            f32x4 b1 = *reinterpret_cast<const f32x4*>(frS + 64 + 8*ut + 4);
            f32x4 c0 = *reinterpret_cast<const f32x4*>(frS + 128 + 8*ut);
            f32x4 c1 = *reinterpret_cast<const f32x4*>(frS + 128 + 8*ut + 4);
            float d[8];
            #pragma unroll
            for (int j = 0; j < 4; ++j) {
                d[j]   = a0[j]*vxI + b0[j]*vyI + c0[j]*vzI;
                d[4+j] = a1[j]*vxI + b1[j]*vyI + c1[j]*vzI;
            }
            #pragma unroll
            for (int j = 0; j < 8; ++j) {
                const f32x2 fdd = {d[j], d[j]};
                const float* wp = wa + (size_t)(8*ut + j) * 128;
                #pragma unroll
                for (int c = 0; c < 8; ++c)
                    accA[c] += ld2(wp + 2*c) * fdd;
            }
        }
    }
    // store out0: 64 B contiguous per lane (8 waves cover cols 0..127)
    {
        float* orow = out + (rbase + row)*OUTD + c16;
        #pragma unroll
        for (int i = 0; i < 4; ++i)
            *reinterpret_cast<float4*>(orow + 4*i) =
                make_float4(accA[2*i][0], accA[2*i][1], accA[2*i+1][0], accA[2*i+1][1]);
    }

    // ---- F3: e pass (LDS v streams) -> e[3] (w101, 8 cols); combine with held accB ----
    f32x2 e0[4], e1[4], e2[4];
    #pragma unroll
    for (int i = 0; i < 4; ++i) {
        e0[i] = (f32x2){0.f, 0.f}; e1[i] = (f32x2){0.f, 0.f}; e2[i] = (f32x2){0.f, 0.f};
    }
    {
        const float* wb = w101 + c8w;
        #pragma unroll 2
        for (int ut = 0; ut < 8; ++ut) {
            f32x4 a0 = *reinterpret_cast<const f32x4*>(frS + 8*ut);
            f32x4 a1 = *reinterpret_cast<const f32x4*>(frS + 8*ut + 4);
            f32x4 b0 = *reinterpret_cast<const f32x4*>(frS + 64 + 8*ut);
            f32x4 b1 = *reinterpret_cast<const f32x4*>(frS + 64 + 8*ut + 4);
            f32x4 c0 = *reinterpret_cast<const f32x4*>(frS + 128 + 8*ut);
            f32x4 c1 = *reinterpret_cast<const f32x4*>(frS + 128 + 8*ut + 4);
            #pragma unroll
            for (int j = 0; j < 8; ++j) {
                const float fa = (j < 4) ? a0[j] : a1[j-4];
                const float fb = (j < 4) ? b0[j] : b1[j-4];
                const float fc = (j < 4) ? c0[j] : c1[j-4];
                const f32x2 faa = {fa, fa}, fbb = {fb, fb}, fcc = {fc, fc};
                const float* wp = wb + (size_t)(8*ut + j) * 64;
                #pragma unroll
                for (int c = 0; c < 4; ++c) {
                    const f32x2 w = ld2(wp + 2*c);
                    e0[c] += w * faa;
                    e1[c] += w * fbb;
                    e2[c] += w * fcc;
                }
            }
        }
    }
    // out1 epilogue + store: 96 B contiguous per lane at 128 + wv*24
    {
        float vals[24];
        #pragma unroll
        for (int c = 0; c < 8; ++c) {
            const float b  = accB[c >> 1][c & 1];
            const float ev0 = e0[c >> 1][c & 1];
            const float ev1 = e1[c >> 1][c & 1];
            const float ev2 = e2[c >> 1][c & 1];
            vals[3*c+0] = vxI*b + s2I*ev0;
            vals[3*c+1] = vyI*b + s2I*ev1;
            vals[3*c+2] = vzI*b + s2I*ev2;
        }
        float* orow = out + (rbase + row)*OUTD + 128 + wv*24;
        #pragma unroll
        for (int i = 0; i < 6; ++i)
            *reinterpret_cast<float4*>(orow + 4*i) =
                make_float4(vals[4*i], vals[4*i+1], vals[4*i+2], vals[4*i+3]);
    }

    // ---- F4: G pass (LDS v streams) -> g[3] (w112, 4 cols); cross epilogue ----
    f32x2 g0[2], g1[2], g2[2];
    #pragma unroll
    for (int i = 0; i < 2; ++i) {
        g0[i] = (f32x2){0.f, 0.f}; g1[i] = (f32x2){0.f, 0.f}; g2[i] = (f32x2){0.f, 0.f};
    }
    {
        const float* wb = w112 + c4w;
        #pragma unroll 2
        for (int ut = 0; ut < 8; ++ut) {
            f32x4 a0 = *reinterpret_cast<const f32x4*>(frS + 8*ut);
            f32x4 a1 = *reinterpret_cast<const f32x4*>(frS + 8*ut + 4);
            f32x4 b0 = *reinterpret_cast<const f32x4*>(frS + 64 + 8*ut);
            f32x4 b1 = *reinterpret_cast<const f32x4*>(frS + 64 + 8*ut + 4);
            f32x4 c0 = *reinterpret_cast<const f32x4*>(frS + 128 + 8*ut);
            f32x4 c1 = *reinterpret_cast<const f32x4*>(frS + 128 + 8*ut + 4);
            #pragma unroll
            for (int j = 0; j < 8; ++j) {
                const float fa = (j < 4) ? a0[j] : a1[j-4];
                const float fb = (j < 4) ? b0[j] : b1[j-4];
                const float fc = (j < 4) ? c0[j] : c1[j-4];
                const f32x2 faa = {fa, fa}, fbb = {fb, fb}, fcc = {fc, fc};
                const float* wp = wb + (size_t)(8*ut + j) * 32;
                #pragma unroll
                for (int c = 0; c < 2; ++c) {
                    const f32x2 w = ld2(wp + 2*c);
                    g0[c] += w * faa;
                    g1[c] += w * fbb;
                    g2[c] += w * fcc;
                }
            }
        }
    }
    // out2 epilogue: cross(G, v)*INV6, 48 B contiguous per lane at 320 + wv*12
    {
        float ov[12];
        #pragma unroll
        for (int wl = 0; wl < 4; ++wl) {
            const float G0 = g0[wl >> 1][wl & 1];
            const float G1 = g1[wl >> 1][wl & 1];
            const float G2 = g2[wl >> 1][wl & 1];
            ov[3*wl+0] = G1*v6z - G2*v6y;
            ov[3*wl+1] = G2*v6x - G0*v6z;
            ov[3*wl+2] = G0*v6y - G1*v6x;
        }
        float* orow = out + (rbase + row)*OUTD + 320 + wv*12;
        #pragma unroll
        for (int i = 0; i < 3; ++i)
            *reinterpret_cast<float4*>(orow + 4*i) =
                make_float4(ov[4*i], ov[4*i+1], ov[4*i+2], ov[4*i+3]);
    }
}

extern "C" void kernel_launch(void* const* d_in, const int* in_sizes, int n_in,
                              void* d_out, int out_size, void* d_ws, size_t ws_size,
                              hipStream_t stream) {
    const float* x1   = (const float*)d_in[0];
    const float* x2   = (const float*)d_in[1];
    const float* w000 = (const float*)d_in[2];
    const float* w011 = (const float*)d_in[3];
    const float* w101 = (const float*)d_in[4];
    const float* w110 = (const float*)d_in[5];
    const float* w112 = (const float*)d_in[6];
    // d_in[7] = w3j111 — folded analytically (cross with v2, scaled 1/sqrt6).
    float* out = (float*)d_out;

    tp_valu_v16<<<dim3(NBLK), dim3(512), 0, stream>>>(
        x1, x2, w000, w011, w101, w110, w112, out);
}

// Round 17
// 305.280 us; speedup vs baseline: 1.2051x; 1.0383x over previous
//
#include <hip/hip_runtime.h>

#define M_ROWS 200000
#define NROWS  64            // rows per block = lanes per wave
#define NBLK   3125          // 200000 / 64, exact
#define DIM1   320
#define OUTD   416
#define FSTR   196           // featV row stride (floats); measured 0 conflicts (R12/R13/R16)
#define LDS_FLOATS (NROWS * FSTR)   // 12544 floats = 50176 B

typedef __attribute__((ext_vector_type(4))) float f32x4;
typedef __attribute__((ext_vector_type(2))) float f32x2;

static __device__ __forceinline__ float4 ld4(const float* p) {
    return *reinterpret_cast<const float4*>(p);
}
static __device__ __forceinline__ f32x2 ld2(const float* p) {
    return *reinterpret_cast<const f32x2*>(p);
}
// force llvm.fma.v2f32 -> v_pk_fma_f32 on gfx950 (R16's `acc += w*f` scalarized:
// VALUBusy stayed 59%; packed selection should put FMA issue at ~half)
static __device__ __forceinline__ f32x2 pkfma(f32x2 a, f32x2 b, f32x2 c) {
    return __builtin_elementwise_fma(a, b, c);
}

__global__ __launch_bounds__(512, 4)
void tp_valu_v17(const float* __restrict__ x1,
                 const float* __restrict__ x2,
                 const float* __restrict__ w000,
                 const float* __restrict__ w011,
                 const float* __restrict__ w101,
                 const float* __restrict__ w110,
                 const float* __restrict__ w112,
                 float* __restrict__ out) {
    __shared__ __align__(16) float featV[LDS_FLOATS];

    constexpr float INV3 = 0.57735026918962576f;   // 1/sqrt(3)
    constexpr float INV6 = 0.40824829046386302f;   // 1/sqrt(6)

    const int t   = threadIdx.x;
    const int row = t & 63;
    const int q   = t >> 6;                        // wave id 0..7
    const int wv  = __builtin_amdgcn_readfirstlane(q);
    const long rbase = (long)blockIdx.x * NROWS;

    const float* x1r = x1 + (rbase + row) * DIM1;
    float* frS = featV + row * FSTR;

    // per-row x2-derived constants, registers for the whole kernel
    const float4 xr2 = ld4(x2 + (rbase + row) * 4);
    const float s2  = xr2.x;
    const float s2I = s2 * INV3;
    const float vxI = xr2.y * INV3, vyI = xr2.z * INV3, vzI = xr2.w * INV3;
    const float v6x = xr2.y * INV6, v6y = xr2.z * INV6, v6z = xr2.w * INV6;

    // ---- stage featV = [v0 (0:64) | v1 (64:128) | v2 (128:192)]; wave q covers u=8q..8q+7 ----
    {
        float qf[24];
        #pragma unroll
        for (int c = 0; c < 6; ++c) {
            float4 v = ld4(x1r + 128 + 24*q + 4*c);
            qf[4*c+0]=v.x; qf[4*c+1]=v.y; qf[4*c+2]=v.z; qf[4*c+3]=v.w;
        }
        #pragma unroll
        for (int i = 0; i < 8; ++i) {
            const int u = 8*q + i;
            frS[u]       = qf[3*i+0];
            frS[64 + u]  = qf[3*i+1];
            frS[128 + u] = qf[3*i+2];
        }
    }
    __syncthreads();                               // the kernel's ONLY barrier

    const int c16 = wv * 16, c8w = wv * 8, c4w = wv * 4;

    // ---- F1: ONE x1s pass (global, per-lane row) -> accA (w000, 16 cols) + accB (w011, 8 cols) ----
    f32x2 accA[8], accB[4];
    #pragma unroll
    for (int i = 0; i < 8; ++i) accA[i] = (f32x2){0.f, 0.f};
    #pragma unroll
    for (int i = 0; i < 4; ++i) accB[i] = (f32x2){0.f, 0.f};
    {
        const float* wa = w000 + c16;
        const float* wb = w011 + c8w;
        #pragma unroll 2
        for (int kt = 0; kt < 16; ++kt) {          // 8 k per tile
            f32x4 xs0 = *reinterpret_cast<const f32x4*>(x1r + kt*8);
            f32x4 xs1 = *reinterpret_cast<const f32x4*>(x1r + kt*8 + 4);
            #pragma unroll
            for (int j = 0; j < 8; ++j) {
                const float fv = (j < 4) ? xs0[j] : xs1[j-4];
                const f32x2 fvv = {fv, fv};
                const float* wpA = wa + (size_t)(kt*8 + j) * 128;
                const float* wpB = wb + (size_t)(kt*8 + j) * 64;
                #pragma unroll
                for (int c = 0; c < 8; ++c)
                    accA[c] = pkfma(ld2(wpA + 2*c), fvv, accA[c]);
                #pragma unroll
                for (int c = 0; c < 4; ++c)
                    accB[c] = pkfma(ld2(wpB + 2*c), fvv, accB[c]);
            }
        }
    }
    {
        const f32x2 s2v = {s2, s2};
        #pragma unroll
        for (int i = 0; i < 8; ++i) accA[i] *= s2v;   // out0 = s2*A + (d @ w110)
    }

    // ---- F2: d pass (LDS v streams) -> accA += (x1v.v2)*INV3 @ w110 ----
    {
        const float* wa = w110 + c16;
        const f32x2 vx2 = {vxI, vxI}, vy2 = {vyI, vyI}, vz2 = {vzI, vzI};
        #pragma unroll 2
        for (int ut = 0; ut < 8; ++ut) {           // 8 u per tile
            f32x2 dp[4];
            #pragma unroll
            for (int p = 0; p < 4; ++p) {          // packed d: pairs of adjacent u
                f32x2 ap = ld2(frS + 8*ut + 2*p);
                f32x2 bp = ld2(frS + 64 + 8*ut + 2*p);
                f32x2 cp = ld2(frS + 128 + 8*ut + 2*p);
                dp[p] = pkfma(cp, vz2, pkfma(bp, vy2, ap * vx2));
            }
            #pragma unroll
            for (int j = 0; j < 8; ++j) {
                const float fd = dp[j >> 1][j & 1];
                const f32x2 fdd = {fd, fd};
                const float* wp = wa + (size_t)(8*ut + j) * 128;
                #pragma unroll
                for (int c = 0; c < 8; ++c)
                    accA[c] = pkfma(ld2(wp + 2*c), fdd, accA[c]);
            }
        }
    }
    // store out0: 64 B contiguous per lane (8 waves cover cols 0..127)
    {
        float* orow = out + (rbase + row)*OUTD + c16;
        #pragma unroll
        for (int i = 0; i < 4; ++i)
            *reinterpret_cast<float4*>(orow + 4*i) =
                make_float4(accA[2*i][0], accA[2*i][1], accA[2*i+1][0], accA[2*i+1][1]);
    }

    // ---- F3: e pass (LDS v streams) -> e[3] (w101, 8 cols); combine with held accB ----
    f32x2 e0[4], e1[4], e2[4];
    #pragma unroll
    for (int i = 0; i < 4; ++i) {
        e0[i] = (f32x2){0.f, 0.f}; e1[i] = (f32x2){0.f, 0.f}; e2[i] = (f32x2){0.f, 0.f};
    }
    {
        const float* wb = w101 + c8w;
        #pragma unroll 2
        for (int ut = 0; ut < 8; ++ut) {
            f32x4 a0 = *reinterpret_cast<const f32x4*>(frS + 8*ut);
            f32x4 a1 = *reinterpret_cast<const f32x4*>(frS + 8*ut + 4);
            f32x4 b0 = *reinterpret_cast<const f32x4*>(frS + 64 + 8*ut);
            f32x4 b1 = *reinterpret_cast<const f32x4*>(frS + 64 + 8*ut + 4);
            f32x4 c0 = *reinterpret_cast<const f32x4*>(frS + 128 + 8*ut);
            f32x4 c1 = *reinterpret_cast<const f32x4*>(frS + 128 + 8*ut + 4);
            #pragma unroll
            for (int j = 0; j < 8; ++j) {
                const float fa = (j < 4) ? a0[j] : a1[j-4];
                const float fb = (j < 4) ? b0[j] : b1[j-4];
                const float fc = (j < 4) ? c0[j] : c1[j-4];
                const f32x2 faa = {fa, fa}, fbb = {fb, fb}, fcc = {fc, fc};
                const float* wp = wb + (size_t)(8*ut + j) * 64;
                #pragma unroll
                for (int c = 0; c < 4; ++c) {
                    const f32x2 w = ld2(wp + 2*c);
                    e0[c] = pkfma(w, faa, e0[c]);
                    e1[c] = pkfma(w, fbb, e1[c]);
                    e2[c] = pkfma(w, fcc, e2[c]);
                }
            }
        }
    }
    // out1 epilogue + store: 96 B contiguous per lane at 128 + wv*24
    {
        float vals[24];
        #pragma unroll
        for (int c = 0; c < 8; ++c) {
            const float b   = accB[c >> 1][c & 1];
            const float ev0 = e0[c >> 1][c & 1];
            const float ev1 = e1[c >> 1][c & 1];
            const float ev2 = e2[c >> 1][c & 1];
            vals[3*c+0] = vxI*b + s2I*ev0;
            vals[3*c+1] = vyI*b + s2I*ev1;
            vals[3*c+2] = vzI*b + s2I*ev2;
        }
        float* orow = out + (rbase + row)*OUTD + 128 + wv*24;
        #pragma unroll
        for (int i = 0; i < 6; ++i)
            *reinterpret_cast<float4*>(orow + 4*i) =
                make_float4(vals[4*i], vals[4*i+1], vals[4*i+2], vals[4*i+3]);
    }

    // ---- F4: G pass (LDS v streams) -> g[3] (w112, 4 cols); cross epilogue ----
    f32x2 g0[2], g1[2], g2[2];
    #pragma unroll
    for (int i = 0; i < 2; ++i) {
        g0[i] = (f32x2){0.f, 0.f}; g1[i] = (f32x2){0.f, 0.f}; g2[i] = (f32x2){0.f, 0.f};
    }
    {
        const float* wb = w112 + c4w;
        #pragma unroll 2
        for (int ut = 0; ut < 8; ++ut) {
            f32x4 a0 = *reinterpret_cast<const f32x4*>(frS + 8*ut);
            f32x4 a1 = *reinterpret_cast<const f32x4*>(frS + 8*ut + 4);
            f32x4 b0 = *reinterpret_cast<const f32x4*>(frS + 64 + 8*ut);
            f32x4 b1 = *reinterpret_cast<const f32x4*>(frS + 64 + 8*ut + 4);
            f32x4 c0 = *reinterpret_cast<const f32x4*>(frS + 128 + 8*ut);
            f32x4 c1 = *reinterpret_cast<const f32x4*>(frS + 128 + 8*ut + 4);
            #pragma unroll
            for (int j = 0; j < 8; ++j) {
                const float fa = (j < 4) ? a0[j] : a1[j-4];
                const float fb = (j < 4) ? b0[j] : b1[j-4];
                const float fc = (j < 4) ? c0[j] : c1[j-4];
                const f32x2 faa = {fa, fa}, fbb = {fb, fb}, fcc = {fc, fc};
                const float* wp = wb + (size_t)(8*ut + j) * 32;
                #pragma unroll
                for (int c = 0; c < 2; ++c) {
                    const f32x2 w = ld2(wp + 2*c);
                    g0[c] = pkfma(w, faa, g0[c]);
                    g1[c] = pkfma(w, fbb, g1[c]);
                    g2[c] = pkfma(w, fcc, g2[c]);
                }
            }
        }
    }
    // out2 epilogue: cross(G, v)*INV6, 48 B contiguous per lane at 320 + wv*12
    {
        float ov[12];
        #pragma unroll
        for (int wl = 0; wl < 4; ++wl) {
            const float G0 = g0[wl >> 1][wl & 1];
            const float G1 = g1[wl >> 1][wl & 1];
            const float G2 = g2[wl >> 1][wl & 1];
            ov[3*wl+0] = G1*v6z - G2*v6y;
            ov[3*wl+1] = G2*v6x - G0*v6z;
            ov[3*wl+2] = G0*v6y - G1*v6x;
        }
        float* orow = out + (rbase + row)*OUTD + 320 + wv*12;
        #pragma unroll
        for (int i = 0; i < 3; ++i)
            *reinterpret_cast<float4*>(orow + 4*i) =
                make_float4(ov[4*i], ov[4*i+1], ov[4*i+2], ov[4*i+3]);
    }
}

extern "C" void kernel_launch(void* const* d_in, const int* in_sizes, int n_in,
                              void* d_out, int out_size, void* d_ws, size_t ws_size,
                              hipStream_t stream) {
    const float* x1   = (const float*)d_in[0];
    const float* x2   = (const float*)d_in[1];
    const float* w000 = (const float*)d_in[2];
    const float* w011 = (const float*)d_in[3];
    const float* w101 = (const float*)d_in[4];
    const float* w110 = (const float*)d_in[5];
    const float* w112 = (const float*)d_in[6];
    // d_in[7] = w3j111 — folded analytically (cross with v2, scaled 1/sqrt6).
    float* out = (float*)d_out;

    tp_valu_v17<<<dim3(NBLK), dim3(512), 0, stream>>>(
        x1, x2, w000, w011, w101, w110, w112, out);
}